// Round 11
// baseline (358.386 us; speedup 1.0000x reference)
//
#include <hip/hip_runtime.h>
#include <hip/hip_bf16.h>

typedef unsigned short ushort_t;
typedef __bf16 bf16x8 __attribute__((ext_vector_type(8)));
typedef float f32x4 __attribute__((ext_vector_type(4)));
typedef unsigned short us8 __attribute__((ext_vector_type(8)));
typedef unsigned int u32;

#define AS1 __attribute__((address_space(1)))
#define AS3 __attribute__((address_space(3)))

#if __has_builtin(__builtin_amdgcn_exp2f)
#define EXP2F __builtin_amdgcn_exp2f
#else
#define EXP2F exp2f
#endif

__device__ __forceinline__ void gld16(const void* g, void* l){
  __builtin_amdgcn_global_load_lds((AS1 void*)(void*)g, (AS3 void*)l, 16, 0, 0);
}
__device__ __forceinline__ f32x4 mfma16(bf16x8 a, bf16x8 b, f32x4 c){
  return __builtin_amdgcn_mfma_f32_16x16x32_bf16(a, b, c, 0, 0, 0);
}
__device__ __forceinline__ unsigned short f2bfu(float f){
  union { float f; unsigned int i; } c; c.f = f;
  unsigned int x = c.i;
  return (unsigned short)((x + 0x7fffu + ((x >> 16) & 1u)) >> 16);  // RNE
}
__device__ __forceinline__ float bfu2f(unsigned short u){
  union { unsigned int i; float f; } c; c.i = ((unsigned int)u) << 16; return c.f;
}
__device__ __forceinline__ float dsilu(float x){ return x / (1.f + __expf(-x)); }
// pack two fp32 -> two bf16 (truncation), 1 v_perm_b32
__device__ __forceinline__ u32 pack_trunc(float a, float b){
  union { float f; u32 u; } ca, cb; ca.f = a; cb.f = b;
#if __has_builtin(__builtin_amdgcn_perm)
  return __builtin_amdgcn_perm(cb.u, ca.u, 0x07060302u);
#else
  return (cb.u & 0xFFFF0000u) | (ca.u >> 16);
#endif
}

// ---------- fused prep: transpose_x (0..1023) | cvt4 (1024..2047) | reorder3 (2048..2559)
__global__ __launch_bounds__(256)
void prep_k(const float* __restrict__ x, ushort_t* __restrict__ xc,
            const float* __restrict__ s0, const float* __restrict__ s1,
            const float* __restrict__ s2, const float* __restrict__ s3,
            ushort_t* __restrict__ d0, ushort_t* __restrict__ d1,
            ushort_t* __restrict__ d2, ushort_t* __restrict__ d3,
            const float* __restrict__ w3, ushort_t* __restrict__ o3,
            ushort_t* __restrict__ zb)
{
  __shared__ float tl[64*68];
  const int bx = blockIdx.x, t = threadIdx.x;
  if (bx < 1024){
    const int b = bx >> 7, ci0 = (bx & 7)*64, px0 = ((bx >> 3) & 15)*64;
    {
      const int ci_l = t>>2, pc = (t&3)*16;
      const float* src = x + (size_t)b*524288 + (size_t)(ci0+ci_l)*1024 + px0 + pc;
      float* d = &tl[ci_l*68 + pc];
      *(float4*)(d)    = *(const float4*)(src);
      *(float4*)(d+4)  = *(const float4*)(src+4);
      *(float4*)(d+8)  = *(const float4*)(src+8);
      *(float4*)(d+12) = *(const float4*)(src+12);
    }
    __syncthreads();
    {
      const int px_l = t>>2, cc = (t&3)*16;
      us8 o0, o1;
#pragma unroll
      for (int i = 0; i < 8; i++) o0[i] = f2bfu(tl[(cc+i)*68 + px_l]);
#pragma unroll
      for (int i = 0; i < 8; i++) o1[i] = f2bfu(tl[(cc+8+i)*68 + px_l]);
      ushort_t* dst = xc + (size_t)b*524288 + (size_t)(px0+px_l)*512 + ci0 + cc;
      *(us8*)dst = o0; *(us8*)(dst+8) = o1;
    }
  } else if (bx < 2048){
    const int bb = bx - 1024;
    const int seg = bb >> 8, blk = bb & 255;
    const float* s = (seg==0?s0:seg==1?s1:seg==2?s2:s3);
    ushort_t* d    = (seg==0?d0:seg==1?d1:seg==2?d2:d3);
    const int n4   = (seg==0?262144:seg==1?524288:seg==2?393216:131072) >> 2;
    for (int i = blk*256 + t; i < n4; i += 256*256){
      const float4 v = *(const float4*)(s + (size_t)i*4);
      ushort4 p; p.x=f2bfu(v.x); p.y=f2bfu(v.y); p.z=f2bfu(v.z); p.w=f2bfu(v.w);
      *(ushort4*)(d + (size_t)i*4) = p;
    }
  } else {
    const int blk = bx - 2048;
    if (blk == 0 && t < 64) zb[t] = 0;
    const float* src = w3 + (size_t)blk*2304;
    ushort_t* dst = o3 + (size_t)blk*2304;
    for (int idx = t; idx < 2304; idx += 256){
      const int ci = idx/9, tap = idx - ci*9;
      dst[tap*256 + ci] = f2bfu(src[idx]);
    }
  }
}

// ---------- MFMA GEMM, double-buffered LDS ----------
// MT=128: 4 waves in 2x2, each computes 64x64 (16 MFMA : 8 ds_read_b128).
// MT=64 : 4 waves in 1x4 (legacy layout, each 64 x NT/4).
template<int BMODE, int EPI, int MT, int NT>
__global__ __launch_bounds__(256, (MT==128)?2:4)
void gemm_k(const ushort_t* __restrict__ A, const int M, const int K, const int kplen,
            const ushort_t* __restrict__ B0, const ushort_t* __restrict__ B1,
            const ushort_t* __restrict__ B2, const ushort_t* __restrict__ B3,
            const int Rb, const long Bbs,
            const float* __restrict__ bnp,
            const float* __restrict__ rw, const float* __restrict__ rh,
            const ushort_t* __restrict__ res, const long res_bs, const int res_rs,
            ushort_t* __restrict__ vtout, const ushort_t* __restrict__ zb,
            void* __restrict__ outp, const long out_bs, const int out_rs)
{
  constexpr int WM = (MT==128) ? 2 : 1;   // wave grid m
  constexpr int WN = 4/WM;                // wave grid n
  constexpr int NW = NT/WN;               // n-width per wave
  constexpr int NF = NW/16;               // n-fragments per wave
  constexpr int ACH = MT/8;               // A 8-row chunks
  constexpr int CH = ACH + NT/8;          // total chunks
  constexpr int CPW = CH/4;               // chunks per wave
  const int m0 = blockIdx.x*MT, n0 = blockIdx.y*NT;
  const int bz = blockIdx.z, b = bz & 7, part = bz >> 3;
  const int tid = threadIdx.x, lane = tid & 63, w = tid >> 6;
  const int q = lane >> 4, l15 = lane & 15;
  const int crow8 = lane >> 3, kq8 = lane & 7;
  const int gq8 = kq8 ^ crow8;
  const int r7 = l15 & 7;
  const int wm = w % WM, wn = w / WM;
  __shared__ __align__(16) ushort_t A_s[2][MT*64];
  __shared__ __align__(16) ushort_t B_s[2][NT*64];

  f32x4 acc[4][NF];
#pragma unroll
  for (int mi = 0; mi < 4; mi++)
#pragma unroll
    for (int ni = 0; ni < NF; ni++) acc[mi][ni] = (f32x4){0.f,0.f,0.f,0.f};

  auto stage = [&](int k0, int buf){
    const int kk = k0 + gq8*8;
#pragma unroll
    for (int p = 0; p < CPW; p++){
      const int c = w*CPW + p;
      if (c < ACH){
        const int row = c*8 + crow8;
        gld16(A + (size_t)(m0 + row)*K + kk, &A_s[buf][c*512]);
      } else {
        const int cb = c - ACH;
        const int row = cb*8 + crow8;
        const ushort_t* gb;
        if (BMODE == 0){
          gb = B0 + (size_t)b*Bbs + (size_t)(n0 + row)*Rb + kk;
        } else if (BMODE == 1){
          const int seg = kk >> 8;
          const ushort_t* sb = (seg==0?B0:seg==1?B1:seg==2?B2:B3);
          const int sstr = (seg < 2) ? 512 : 256;
          const long sbs = (seg < 2) ? 524288L : 262144L;
          gb = sb + (size_t)b*sbs + (size_t)(n0 + row)*sstr + (kk & 255);
        } else {
          const int tap = k0 >> 8;
          const int ci = (k0 & 255) + gq8*8;
          const int oy = tap/3 - 1, ox = tap - (tap/3)*3 - 1;
          const int px = n0 + row;
          const int yy = (px >> 5) + oy, xx = (px & 31) + ox;
          const bool vld = ((unsigned)yy < 32u) && ((unsigned)xx < 32u);
          gb = vld ? (B0 + (size_t)b*Bbs + (size_t)(yy*32 + xx)*Rb + ci) : zb;
        }
        gld16(gb, &B_s[buf][cb*512]);
      }
    }
  };

  const int kbeg = part*kplen, kend_ = kbeg + kplen;
  stage(kbeg, 0);
  int cur = 0;
  for (int k0 = kbeg; k0 < kend_; k0 += 64){
    __syncthreads();                       // buf[cur] landed; prev compute done
    if (k0 + 64 < kend_) stage(k0 + 64, cur ^ 1);
#pragma unroll
    for (int ks = 0; ks < 2; ks++){
      const int slot = (ks*4 + q) ^ r7;
      bf16x8 af[4], bfr[NF];
#pragma unroll
      for (int mi = 0; mi < 4; mi++)
        af[mi] = __builtin_bit_cast(bf16x8,
            *(const us8*)&A_s[cur][(wm*64 + mi*16 + l15)*64 + slot*8]);
#pragma unroll
      for (int ni = 0; ni < NF; ni++)
        bfr[ni] = __builtin_bit_cast(bf16x8,
            *(const us8*)&B_s[cur][(wn*NW + ni*16 + l15)*64 + slot*8]);
#pragma unroll
      for (int mi = 0; mi < 4; mi++)
#pragma unroll
        for (int ni = 0; ni < NF; ni++)
          acc[mi][ni] = mfma16(af[mi], bfr[ni], acc[mi][ni]);
    }
    cur ^= 1;
  }

  const int n_w = n0 + wn*NW;
#pragma unroll
  for (int mi = 0; mi < 4; mi++){
    const int mb = m0 + wm*64 + mi*16 + q*4;
    float sc[4], off[4];
    if (EPI != 1 && EPI != 4){
      const float4 g  = *(const float4*)(bnp + mb);
      const float4 be = *(const float4*)(bnp + M + mb);
      const float4 mu = *(const float4*)(bnp + 2*M + mb);
      const float4 va = *(const float4*)(bnp + 3*M + mb);
      sc[0] = g.x/sqrtf(va.x+1e-3f); off[0] = be.x - mu.x*sc[0];
      sc[1] = g.y/sqrtf(va.y+1e-3f); off[1] = be.y - mu.y*sc[1];
      sc[2] = g.z/sqrtf(va.z+1e-3f); off[2] = be.z - mu.z*sc[2];
      sc[3] = g.w/sqrtf(va.w+1e-3f); off[3] = be.w - mu.w*sc[3];
    }
    const int region = mb >> 8;
#pragma unroll
    for (int ni = 0; ni < NF; ni++){
      const int n_g = n_w + ni*16 + l15;
      f32x4 v = acc[mi][ni];
      if (EPI == 4){
        *(float4*)((float*)outp + ((size_t)(part*8 + b)*1024 + n_g)*256 + mb) =
            (float4){v[0], v[1], v[2], v[3]};
        continue;
      }
      float o[4];
#pragma unroll
      for (int r = 0; r < 4; r++){
        float xv = v[r];
        if (EPI == 1){
          if (region == 0) xv *= 0.18033688011112042f;   // 0.125 * log2(e)
          else if (region == 1){
            const int c64 = mb + r - 256;
            xv += rw[c64*32 + (n_g & 31)] + rh[c64*32 + (n_g >> 5)];
          }
        } else {
          xv = dsilu(xv*sc[r] + off[r]);
          if (EPI == 2)
            xv += bfu2f(res[(size_t)b*res_bs + (size_t)n_g*res_rs + mb + r]);
        }
        o[r] = xv;
      }
      if (EPI == 3){
        float* of = (float*)outp + (size_t)b*out_bs;
#pragma unroll
        for (int r = 0; r < 4; r++) of[(size_t)(mb + r)*1024 + n_g] = o[r];
      } else if (EPI == 1 && region == 2){
#pragma unroll
        for (int r = 0; r < 4; r++)
          vtout[(size_t)b*262144 + (size_t)(mb + r - 512)*1024 + n_g] = f2bfu(o[r]);
      } else {
        ushort4 pk; pk.x=f2bfu(o[0]); pk.y=f2bfu(o[1]); pk.z=f2bfu(o[2]); pk.w=f2bfu(o[3]);
        *(ushort4*)((ushort_t*)outp + (size_t)b*out_bs + (size_t)n_g*out_rs + mb) = pk;
      }
    }
  }
}

// ---------- split-K reduce (unchanged) ----------
__global__ __launch_bounds__(256)
void reduce3_k(const float* __restrict__ pbuf, const float* __restrict__ bnp,
               ushort_t* __restrict__ out)
{
  const int idx = blockIdx.x*256 + threadIdx.x;
  const int co = (idx & 63)*4;
  const size_t e = (size_t)idx*4;
  float4 a = *(const float4*)(pbuf + e);
  const float4 c = *(const float4*)(pbuf + 2097152 + e);
  a.x += c.x; a.y += c.y; a.z += c.z; a.w += c.w;
  const float4 g  = *(const float4*)(bnp + co);
  const float4 be = *(const float4*)(bnp + 256 + co);
  const float4 mu = *(const float4*)(bnp + 512 + co);
  const float4 va = *(const float4*)(bnp + 768 + co);
  float s0 = g.x/sqrtf(va.x+1e-3f), s1 = g.y/sqrtf(va.y+1e-3f);
  float s2 = g.z/sqrtf(va.z+1e-3f), s3 = g.w/sqrtf(va.w+1e-3f);
  ushort4 pk;
  pk.x = f2bfu(dsilu((a.x - mu.x)*s0 + be.x));
  pk.y = f2bfu(dsilu((a.y - mu.y)*s1 + be.y));
  pk.z = f2bfu(dsilu((a.z - mu.z)*s2 + be.z));
  pk.w = f2bfu(dsilu((a.w - mu.w)*s3 + be.w));
  *(ushort4*)(out + e) = pk;
}

// ---------- flash attention v5: BJ=128, S^T softmax, l via ones-MFMA ----------
__global__ __launch_bounds__(256)
void attn_k(const ushort_t* __restrict__ qk, const ushort_t* __restrict__ vt,
            ushort_t* __restrict__ out)
{
  const int it = blockIdx.x, h = blockIdx.y, b = blockIdx.z;
  const int tid = threadIdx.x, lane = tid & 63, w = tid >> 6;
  const int q = lane >> 4, l15 = lane & 15;
  const int i0 = it*64;
  __shared__ __align__(16) ushort_t K_s[2][8192];
  __shared__ __align__(16) ushort_t V_s[2][8192];
  __shared__ __align__(16) ushort_t P_s[8192];

  const ushort_t* qkb = qk + (size_t)b*524288;
  const ushort_t* vtb = vt + (size_t)b*262144 + (size_t)h*65536;

  const int k_row8 = lane >> 3;
  const int k_gq   = (lane & 7) ^ k_row8;
  const int v_row4 = lane >> 4;
  const int v_s16  = lane & 15;
  const int rs7    = l15 & 7;

  bf16x8 qf[2];
  {
    const ushort_t* qr = qkb + (size_t)(i0 + w*16 + l15)*512 + h*64 + q*8;
    qf[0] = __builtin_bit_cast(bf16x8, *(const us8*)qr);
    qf[1] = __builtin_bit_cast(bf16x8, *(const us8*)(qr + 32));
  }
  const us8 ones_u = { 0x3F80,0x3F80,0x3F80,0x3F80,0x3F80,0x3F80,0x3F80,0x3F80 };
  const bf16x8 onesf = __builtin_bit_cast(bf16x8, ones_u);

  f32x4 oacc[4];
#pragma unroll
  for (int nd = 0; nd < 4; nd++) oacc[nd] = (f32x4){0.f,0.f,0.f,0.f};
  f32x4 lacc = (f32x4){0.f,0.f,0.f,0.f};
  float m_s = -3e38f;

#define STAGE(JT, BUF) {                                                        \
    const int j0s = (JT)*128;                                                   \
    _Pragma("unroll")                                                           \
    for (int p = 0; p < 4; p++){                                                \
      const int c = w*4 + p;                                                    \
      const int krow = c*8 + k_row8;                                            \
      gld16(qkb + (size_t)(j0s + krow)*512 + 256 + h*64 + k_gq*8, &K_s[BUF][c*512]); \
      const int vrow = c*4 + v_row4;                                            \
      const int vg = v_s16 ^ (vrow & 15);                                       \
      gld16(vtb + (size_t)vrow*1024 + j0s + vg*8, &V_s[BUF][c*512]);            \
    }                                                                           \
  }

  STAGE(0, 0);
  int cur = 0;
  for (int jt = 0; jt < 8; jt++){
    __syncthreads();
    if (jt < 7){ STAGE(jt+1, cur^1); }
    // S^T = K Q^T : rows j (8 frag-groups), cols i = l15
    f32x4 sacc[8];
#pragma unroll
    for (int ni = 0; ni < 8; ni++) sacc[ni] = (f32x4){0.f,0.f,0.f,0.f};
#pragma unroll
    for (int ks = 0; ks < 2; ks++){
      const int slot = (ks*4 + q) ^ rs7;
#pragma unroll
      for (int ni = 0; ni < 8; ni++){
        const bf16x8 kf = __builtin_bit_cast(bf16x8,
            *(const us8*)&K_s[cur][(ni*16 + l15)*64 + slot*8]);
        sacc[ni] = mfma16(kf, qf[ks], sacc[ni]);
      }
    }
    // online softmax (exp2 domain); lane owns 32 j of row i = w*16+l15
    float mx = sacc[0][0];
#pragma unroll
    for (int ni = 0; ni < 8; ni++)
#pragma unroll
      for (int r = 0; r < 4; r++) mx = fmaxf(mx, sacc[ni][r]);
    mx = fmaxf(mx, __shfl_xor(mx, 16));
    mx = fmaxf(mx, __shfl_xor(mx, 32));
    const float mnew = fmaxf(m_s, mx);
    const float alpha = EXP2F(m_s - mnew);
    m_s = mnew;
    float p[8][4];
#pragma unroll
    for (int ni = 0; ni < 8; ni++)
#pragma unroll
      for (int r = 0; r < 4; r++) p[ni][r] = EXP2F(sacc[ni][r] - mnew);
    // rescale O and l (rows i = w*16 + q*4 + r)
#pragma unroll
    for (int r = 0; r < 4; r++){
      const float a_r = __shfl(alpha, q*4 + r);
#pragma unroll
      for (int nd = 0; nd < 4; nd++) oacc[nd][r] *= a_r;
      lacc[r] *= a_r;
    }
    // write P[i][j], trunc-packed, swizzled
    {
      const int prow = w*16 + l15;
#pragma unroll
      for (int ni = 0; ni < 8; ni++){
        uint2 pk;
        pk.x = pack_trunc(p[ni][0], p[ni][1]);
        pk.y = pack_trunc(p[ni][2], p[ni][3]);
        const int phys = (ni*2 + (q>>1)) ^ l15;
        *(uint2*)&P_s[prow*128 + phys*8 + (q&1)*4] = pk;
      }
    }
    // O += P V ; l += P * ones (intra-wave P dependency)
#pragma unroll
    for (int ks = 0; ks < 4; ks++){
      const int slotp = (ks*4 + q) ^ l15;
      const bf16x8 pa = __builtin_bit_cast(bf16x8,
          *(const us8*)&P_s[(w*16 + l15)*128 + slotp*8]);
      lacc = mfma16(pa, onesf, lacc);
#pragma unroll
      for (int nd = 0; nd < 4; nd++){
        const bf16x8 vb = __builtin_bit_cast(bf16x8,
            *(const us8*)&V_s[cur][(nd*16 + l15)*128 + slotp*8]);
        oacc[nd] = mfma16(pa, vb, oacc[nd]);
      }
    }
    cur ^= 1;
  }
#undef STAGE
  ushort_t* ob = out + (size_t)b*262144;
#pragma unroll
  for (int r = 0; r < 4; r++){
    const float rinv = 1.f / lacc[r];
    const size_t rowo = (size_t)(i0 + w*16 + q*4 + r)*256 + h*64 + l15;
#pragma unroll
    for (int nd = 0; nd < 4; nd++)
      ob[rowo + nd*16] = f2bfu(oacc[nd][r]*rinv);
  }
}

// ---------- host ----------
extern "C" void kernel_launch(void* const* d_in, const int* in_sizes, int n_in,
                              void* d_out, int out_size, void* d_ws, size_t ws_size,
                              hipStream_t stream)
{
  const float* x       = (const float*)d_in[0];
  const float* cv1_w   = (const float*)d_in[1];
  const float* cv1_bn  = (const float*)d_in[2];
  const float* cv2_w   = (const float*)d_in[3];
  const float* cv2_bn  = (const float*)d_in[4];
  const float* mcv1_w  = (const float*)d_in[5];
  const float* mcv1_bn = (const float*)d_in[6];
  const float* mqkv_w  = (const float*)d_in[7];
  const float* mrw     = (const float*)d_in[8];
  const float* mrh     = (const float*)d_in[9];
  const float* mcv2_w  = (const float*)d_in[10];
  const float* mcv2_bn = (const float*)d_in[11];

  ushort_t* uw = (ushort_t*)d_ws;
  ushort_t* x_cl    = uw;                  // 4,194,304
  ushort_t* t_cl    = x_cl    + 4194304;   // 4,194,304
  ushort_t* wb_cv1  = t_cl    + 4194304;   //   262,144
  ushort_t* wb_cv2  = wb_cv1  + 262144;    //   524,288
  ushort_t* wb_qkv  = wb_cv2  + 524288;    //   393,216
  ushort_t* wb_mcv2 = wb_qkv  + 393216;    //   131,072
  ushort_t* wb_mcv1 = wb_mcv2 + 131072;    // 1,179,648
  ushort_t* z1_cl   = wb_mcv1 + 1179648;   // 2,097,152
  ushort_t* qk_cl   = z1_cl   + 2097152;   // 4,194,304  [b][px][512]
  ushort_t* vt_b    = qk_cl   + 4194304;   // 2,097,152  [b][256][1024]
  ushort_t* att_cl  = vt_b    + 2097152;   // 2,097,152
  ushort_t* y2_cl   = att_cl  + 2097152;   // 2,097,152
  ushort_t* y3_cl   = y2_cl   + 2097152;   // 2,097,152
  float*    part_f  = (float*)(y3_cl + 2097152);  // 4,194,304 floats (16 MB)
  ushort_t* zbuf    = (ushort_t*)(part_f + 4194304); // 64 zeros

  const dim3 blk(256);

  prep_k<<<dim3(2560), blk, 0, stream>>>(x, x_cl,
      cv1_w, cv2_w, mqkv_w, mcv2_w, wb_cv1, wb_cv2, wb_qkv, wb_mcv2,
      mcv1_w, wb_mcv1, zbuf);

  // cv1: [512 co][512 ci] x x_cl -> t_cl (128x128 tiles, 256 blocks)
  gemm_k<0,0,128,128><<<dim3(4,8,8), blk, 0, stream>>>(
      wb_cv1, 512, 512, 512, x_cl, nullptr, nullptr, nullptr, 512, 524288L,
      cv1_bn, nullptr, nullptr, nullptr, 0, 0, nullptr, nullptr, t_cl, 524288L, 512);

  const ushort_t* yi = t_cl + 256;  long yi_bs = 524288; int yi_rs = 512;
  ushort_t* youts[2] = { y2_cl, y3_cl };
  for (int i = 0; i < 2; i++){
    // conv3x3 implicit-im2col from yi, split-K x2 (128x128 tiles, 256 blocks)
    gemm_k<2,4,128,128><<<dim3(2,8,16), blk, 0, stream>>>(
        wb_mcv1 + (size_t)i*589824, 256, 2304, 1152, yi, nullptr, nullptr, nullptr,
        yi_rs, yi_bs,
        nullptr, nullptr, nullptr, nullptr, 0, 0, nullptr, zbuf, part_f, 0, 0);
    reduce3_k<<<dim3(2048), blk, 0, stream>>>(part_f, mcv1_bn + i*1024, z1_cl);
    // qkv (128x128 tiles, 384 blocks): q/k -> qk_cl [px][512], v -> vt_b NCHW
    gemm_k<0,1,128,128><<<dim3(6,8,8), blk, 0, stream>>>(
        wb_qkv + (size_t)i*196608, 768, 256, 256, z1_cl, nullptr, nullptr, nullptr, 256, 262144L,
        nullptr, mrw + i*8192, mrh + i*8192, nullptr, 0, 0, vt_b, nullptr, qk_cl, 524288L, 512);
    attn_k<<<dim3(16,4,8), blk, 0, stream>>>(qk_cl, vt_b, att_cl);
    // mcv2 + residual (64x64 tiles, 512 blocks)
    gemm_k<0,2,64,64><<<dim3(4,16,8), blk, 0, stream>>>(
        wb_mcv2 + (size_t)i*65536, 256, 256, 256, att_cl, nullptr, nullptr, nullptr, 256, 262144L,
        mcv2_bn + i*1024, nullptr, nullptr, yi, yi_bs, yi_rs, nullptr, nullptr,
        youts[i], 262144L, 256);
    yi = youts[i]; yi_bs = 262144; yi_rs = 256;
  }

  // concat [y0|y1|y2|y3] 1024ch -> 512, fp32 NCHW out (128x128 tiles, 256 blocks)
  gemm_k<1,3,128,128><<<dim3(4,8,8), blk, 0, stream>>>(
      wb_cv2, 512, 1024, 1024, t_cl, t_cl + 256, y2_cl, y3_cl, 0, 0,
      cv2_bn, nullptr, nullptr, nullptr, 0, 0, nullptr, nullptr, (float*)d_out, 524288L, 0);
}